// Round 13
// baseline (68.905 us; speedup 1.0000x reference)
//
#include <hip/hip_runtime.h>

typedef __bf16 bf16_t;
typedef __bf16 bf16x8 __attribute__((ext_vector_type(8)));
typedef __bf16 bf16x4 __attribute__((ext_vector_type(4)));
typedef float  f32x4  __attribute__((ext_vector_type(4)));
typedef _Float16 f16_t;
typedef _Float16 f16x8 __attribute__((ext_vector_type(8)));

#define TSEQ 4096
#define SEGS 12

// lgkm-only barrier: in-flight global prefetches survive it.
__device__ __forceinline__ void barrier_lds() {
    __builtin_amdgcn_sched_barrier(0);
    asm volatile("s_waitcnt lgkmcnt(0)" ::: "memory");
    __builtin_amdgcn_s_barrier();
    __builtin_amdgcn_sched_barrier(0);
}

// ---------------------------------------------------------------------------
// wsplit: W[1024][64] (q,k,v fp32) -> wT[192][1024] bf16 (transposed).
// Wq pre-scaled by 0.125*log2(e) so attention scores land in exp2 domain.
// ---------------------------------------------------------------------------
__global__ __launch_bounds__(256) void wsplit_k(
    const float* __restrict__ Wq, const float* __restrict__ Wk,
    const float* __restrict__ Wv, bf16_t* __restrict__ wT)
{
    __shared__ bf16_t th[64][72];
    const int mat = blockIdx.x >> 4;
    const int kb  = (blockIdx.x & 15) * 64;
    const float* W = (mat == 0) ? Wq : ((mat == 1) ? Wk : Wv);
    const float scale = (mat == 0) ? 0.18033688011112042f : 1.0f;
    const int t  = threadIdx.x;
    const int kl = t >> 2;
    const int dc = (t & 3) * 16;
    #pragma unroll
    for (int i = 0; i < 4; ++i) {
        float4 v = *reinterpret_cast<const float4*>(W + (long)(kb + kl) * 64 + dc + 4 * i);
        th[dc + 4*i + 0][kl] = (bf16_t)(v.x * scale);
        th[dc + 4*i + 1][kl] = (bf16_t)(v.y * scale);
        th[dc + 4*i + 2][kl] = (bf16_t)(v.z * scale);
        th[dc + 4*i + 3][kl] = (bf16_t)(v.w * scale);
    }
    __syncthreads();
    const int d  = t >> 2;
    const int kc = (t & 3) * 16;
    bf16x8 a0 = *reinterpret_cast<const bf16x8*>(&th[d][kc]);
    bf16x8 a1 = *reinterpret_cast<const bf16x8*>(&th[d][kc + 8]);
    long o = (long)(mat * 64 + d) * 1024 + kb + kc;
    *reinterpret_cast<bf16x8*>(wT + o)     = a0;
    *reinterpret_cast<bf16x8*>(wT + o + 8) = a1;
}

// ---------------------------------------------------------------------------
// proj v3: [8192][192] = X @ W^T.  512 blocks x 16 rows, ALL 192 cols per
// block -> X read from HBM exactly once (32 MB).  4 waves pure N-split
// (wave = 16 rows x 3 tiles); A-frags shared via L1.  W slice (192x64/step,
// 24 KB) dbuf in LDS pad-72 (conflict-free b128), staged T14 (6 named regs),
// lgkm-only barrier, 16 K-steps.  W itself is L2-resident (384 KB).
// ---------------------------------------------------------------------------
__global__ __launch_bounds__(256, 2) void proj_mfma(
    const float* __restrict__ X, const bf16_t* __restrict__ wT,
    bf16_t* __restrict__ qh, bf16_t* __restrict__ kh, bf16_t* __restrict__ vt)
{
    __shared__ __align__(16) unsigned char smem[55296];
    bf16_t (*wl)[192][72] = reinterpret_cast<bf16_t(*)[192][72]>(smem);  // [2][192][72]
    float  (*vtl)[20]     = reinterpret_cast<float(*)[20]>(smem);        // [64][20] union

    const int tid = threadIdx.x, lane = tid & 63;
    const int w   = tid >> 6;            // wave = N-split (3 tiles each)
    const int q4 = lane & 15, g = lane >> 4;
    const long R0 = (long)blockIdx.x * 16;

    const float* xrow = X + (R0 + q4) * 1024 + 8 * g;

    // W staging: thread covers rows trow+32i (i<6), col chunk c (16B)
    const int trow = tid >> 3, c = (tid & 7) * 8;
    const bf16_t* wsrc = wT + (long)trow * 1024 + c;

    bf16x8 wr0, wr1, wr2, wr3, wr4, wr5;
    float4 xE[4], xO[4];
    f32x4 acc[3] = {};

    auto loadW = [&](int t) {
        const bf16_t* s = wsrc + t * 64;
        wr0 = *reinterpret_cast<const bf16x8*>(s);
        wr1 = *reinterpret_cast<const bf16x8*>(s + 32 * 1024);
        wr2 = *reinterpret_cast<const bf16x8*>(s + 64 * 1024);
        wr3 = *reinterpret_cast<const bf16x8*>(s + 96 * 1024);
        wr4 = *reinterpret_cast<const bf16x8*>(s + 128 * 1024);
        wr5 = *reinterpret_cast<const bf16x8*>(s + 160 * 1024);
    };
    auto writeW = [&](int buf) {
        *reinterpret_cast<bf16x8*>(&wl[buf][trow      ][c]) = wr0;
        *reinterpret_cast<bf16x8*>(&wl[buf][trow +  32][c]) = wr1;
        *reinterpret_cast<bf16x8*>(&wl[buf][trow +  64][c]) = wr2;
        *reinterpret_cast<bf16x8*>(&wl[buf][trow +  96][c]) = wr3;
        *reinterpret_cast<bf16x8*>(&wl[buf][trow + 128][c]) = wr4;
        *reinterpret_cast<bf16x8*>(&wl[buf][trow + 160][c]) = wr5;
    };
    auto loadX = [&](int t, float4 (&xc)[4]) {
        xc[0] = *reinterpret_cast<const float4*>(xrow + t * 64);
        xc[1] = *reinterpret_cast<const float4*>(xrow + t * 64 + 4);
        xc[2] = *reinterpret_cast<const float4*>(xrow + t * 64 + 32);
        xc[3] = *reinterpret_cast<const float4*>(xrow + t * 64 + 36);
    };

    loadW(0); writeW(0);
    loadW(1);
    loadX(0, xE); loadX(1, xO);
    asm volatile("" ::: "memory");
    barrier_lds();

    auto stepf = [&](int t, float4 (&xc)[4]) {
        if (t + 1 < 16) {                    // stage W(t+1), issue W(t+2)
            writeW((t + 1) & 1);
            loadW(t + 2 < 16 ? t + 2 : 15);
        }
        bf16x8 a0 = {(bf16_t)xc[0].x, (bf16_t)xc[0].y, (bf16_t)xc[0].z, (bf16_t)xc[0].w,
                     (bf16_t)xc[1].x, (bf16_t)xc[1].y, (bf16_t)xc[1].z, (bf16_t)xc[1].w};
        bf16x8 a1 = {(bf16_t)xc[2].x, (bf16_t)xc[2].y, (bf16_t)xc[2].z, (bf16_t)xc[2].w,
                     (bf16_t)xc[3].x, (bf16_t)xc[3].y, (bf16_t)xc[3].z, (bf16_t)xc[3].w};
        if (t + 2 < 16) loadX(t + 2, xc);    // 2-step-ahead X reissue
        asm volatile("" ::: "memory");
        __builtin_amdgcn_s_setprio(1);
        #pragma unroll
        for (int j = 0; j < 3; ++j) {
            const int lr = (3 * w + j) * 16 + q4;
            bf16x8 b0 = *reinterpret_cast<const bf16x8*>(&wl[t & 1][lr][8 * g]);
            bf16x8 b1 = *reinterpret_cast<const bf16x8*>(&wl[t & 1][lr][8 * g + 32]);
            acc[j] = __builtin_amdgcn_mfma_f32_16x16x32_bf16(a0, b0, acc[j], 0, 0, 0);
            acc[j] = __builtin_amdgcn_mfma_f32_16x16x32_bf16(a1, b1, acc[j], 0, 0, 0);
        }
        __builtin_amdgcn_s_setprio(0);
        barrier_lds();
    };
    #pragma unroll
    for (int tt = 0; tt < 16; tt += 2) { stepf(tt, xE); stepf(tt + 1, xO); }

    // epilogue: nt<4 -> q, nt<8 -> k, else v staged in vtl for transpose
    #pragma unroll
    for (int j = 0; j < 3; ++j) {
        const int nt = 3 * w + j;
        #pragma unroll
        for (int r = 0; r < 4; ++r) {
            const long row = R0 + 4 * g + r;
            const float vv = acc[j][r];
            if (nt < 4)      qh[row * 64 + nt * 16 + q4] = (bf16_t)vv;
            else if (nt < 8) kh[row * 64 + (nt - 4) * 16 + q4] = (bf16_t)vv;
            else             vtl[(nt - 8) * 16 + q4][4 * g + r] = vv;
        }
    }
    barrier_lds();
    {
        const int d = tid >> 2, rc = (tid & 3) * 4;
        bf16x4 o;
        #pragma unroll
        for (int i = 0; i < 4; ++i) o[i] = (bf16_t)vtl[d][rc + i];
        *reinterpret_cast<bf16x4*>(vt + (long)d * 8192 + R0 + rc) = o;
    }
}

// ---------------------------------------------------------------------------
// attn: flash, block = 64 queries (4 waves M-split), seg round-robin causal
// split (SEGS=12).  K/V SINGLE-buffered in LDS (27.6KB -> 5 blocks/CU),
// staged T14 (reg-held one chunk ahead); conditional lgkm barriers per
// chunk + MANDATORY barrier before epilogue (ot unions P across waves —
// r12's race).  Softmax in-place on sacc; exact defer-rescale.  exp2.
// ---------------------------------------------------------------------------
__global__ __launch_bounds__(256, 5) void attn_mfma(
    const bf16_t* __restrict__ qh, const bf16_t* __restrict__ kh,
    const bf16_t* __restrict__ vt,
    f16_t* __restrict__ pO, float* __restrict__ pm, float* __restrict__ pl)
{
    __shared__ __align__(16) unsigned char smem[27648];
    bf16_t (*kl)[72]      = reinterpret_cast<bf16_t(*)[72]>(smem);               // [64][72]
    bf16_t (*vl)[72]      = reinterpret_cast<bf16_t(*)[72]>(smem + 9216);        // [64][72]
    bf16_t (*P)[8][16][8] = reinterpret_cast<bf16_t(*)[8][16][8]>(smem + 18432); // [4] 8192B
    f16_t  (*ot)[16][72]  = reinterpret_cast<f16_t(*)[16][72]>(smem + 18432);    // [4] 9216B union

    const int tid = threadIdx.x, lane = tid & 63, w = tid >> 6;
    const int q4 = lane & 15, g = lane >> 4;
    const int bx = blockIdx.x, b = blockIdx.y;
    const int tile = 63 - bx / SEGS;     // heavy tiles first
    const int seg  = bx % SEGS;
    const int C = tile + 1;
    if (seg >= C) return;
    const long base = (long)b * TSEQ;
    const int r0 = tile * 64 + 16 * w;

    const bf16_t* qr = qh + (base + r0 + q4) * 64 + 8 * g;
    const bf16x8 qf0 = *reinterpret_cast<const bf16x8*>(qr);
    const bf16x8 qf1 = *reinterpret_cast<const bf16x8*>(qr + 32);

    const int srow = tid >> 2, sc = (tid & 3) * 16;
    const bf16_t* ksrc = kh + (base + srow) * 64 + sc;
    const bf16_t* vsrc = vt + (long)srow * 8192 + base + sc;
    bf16x8 kr0, kr1, vr0, vr1;
    auto loadKV = [&](int kb) {
        kr0 = *reinterpret_cast<const bf16x8*>(ksrc + (long)kb * 64);
        kr1 = *reinterpret_cast<const bf16x8*>(ksrc + (long)kb * 64 + 8);
        vr0 = *reinterpret_cast<const bf16x8*>(vsrc + kb);
        vr1 = *reinterpret_cast<const bf16x8*>(vsrc + kb + 8);
    };
    auto writeKV = [&]() {
        *reinterpret_cast<bf16x8*>(&kl[srow][sc])     = kr0;
        *reinterpret_cast<bf16x8*>(&kl[srow][sc + 8]) = kr1;
        *reinterpret_cast<bf16x8*>(&vl[srow][sc])     = vr0;
        *reinterpret_cast<bf16x8*>(&vl[srow][sc + 8]) = vr1;
    };

    float m = -1e30f, l = 0.f;
    f32x4 oacc[4] = {};

    loadKV(seg << 6);
    writeKV();
    { int c1 = seg + SEGS; loadKV((c1 < C ? c1 : seg) << 6); }
    asm volatile("" ::: "memory");
    barrier_lds();

    for (int c = seg; c < C; c += SEGS) {
        const int kb = c << 6;

        // ---- QK^T (swapped): S^T rows = keys, cols = queries
        f32x4 sacc[4];
        __builtin_amdgcn_s_setprio(1);
        #pragma unroll
        for (int kt = 0; kt < 4; ++kt) {
            bf16x8 kf0 = *reinterpret_cast<const bf16x8*>(&kl[kt * 16 + q4][8 * g]);
            bf16x8 kf1 = *reinterpret_cast<const bf16x8*>(&kl[kt * 16 + q4][8 * g + 32]);
            f32x4 a = {};
            a = __builtin_amdgcn_mfma_f32_16x16x32_bf16(kf0, qf0, a, 0, 0, 0);
            a = __builtin_amdgcn_mfma_f32_16x16x32_bf16(kf1, qf1, a, 0, 0, 0);
            sacc[kt] = a;
        }
        __builtin_amdgcn_s_setprio(0);

        // ---- causal mask: diagonal chunk only (uniform branch)
        if (c == C - 1) {
            const int kk = kb + 4 * g;
            #pragma unroll
            for (int kt = 0; kt < 4; ++kt)
                #pragma unroll
                for (int r = 0; r < 4; ++r)
                    if (kk + kt * 16 + r > r0 + q4) sacc[kt][r] = -1e30f;
        }

        // ---- per-query max
        float mx = sacc[0][0];
        #pragma unroll
        for (int kt = 0; kt < 4; ++kt)
            #pragma unroll
            for (int r = 0; r < 4; ++r) mx = fmaxf(mx, sacc[kt][r]);
        mx = fmaxf(mx, __shfl_xor(mx, 16));
        mx = fmaxf(mx, __shfl_xor(mx, 32));

        // ---- exp2 in place; exact defer-rescale when max didn't grow
        float lsum = 0.f;
        if (__all(mx <= m)) {
            #pragma unroll
            for (int kt = 0; kt < 4; ++kt)
                #pragma unroll
                for (int r = 0; r < 4; ++r) {
                    sacc[kt][r] = __builtin_exp2f(sacc[kt][r] - m);
                    lsum += sacc[kt][r];
                }
        } else {
            const float mnew = fmaxf(m, mx);
            const float alpha = __builtin_exp2f(m - mnew);
            m = mnew;
            #pragma unroll
            for (int kt = 0; kt < 4; ++kt)
                #pragma unroll
                for (int r = 0; r < 4; ++r) {
                    sacc[kt][r] = __builtin_exp2f(sacc[kt][r] - mnew);
                    lsum += sacc[kt][r];
                }
            #pragma unroll
            for (int dt = 0; dt < 4; ++dt) oacc[dt] *= alpha;
            l *= alpha;
        }
        lsum += __shfl_xor(lsum, 16);
        lsum += __shfl_xor(lsum, 32);
        l += lsum;

        // ---- pack P (bf16) into this wave's LDS tile
        #pragma unroll
        for (int kt = 0; kt < 4; ++kt) {
            const int cb = 2 * kt + (g >> 1);
            const int ki = (g & 1) << 2;
            bf16x4 hv = {(bf16_t)sacc[kt][0], (bf16_t)sacc[kt][1],
                         (bf16_t)sacc[kt][2], (bf16_t)sacc[kt][3]};
            *reinterpret_cast<bf16x4*>(&P[w][cb][q4][ki]) = hv;
        }
        bf16x8 ph0 = *reinterpret_cast<const bf16x8*>(&P[w][g][q4][0]);
        bf16x8 ph1 = *reinterpret_cast<const bf16x8*>(&P[w][4 + g][q4][0]);

        // ---- PV: O^T += V^T x P^T
        __builtin_amdgcn_s_setprio(1);
        #pragma unroll
        for (int dt = 0; dt < 4; ++dt) {
            bf16x8 va0 = *reinterpret_cast<const bf16x8*>(&vl[dt * 16 + q4][8 * g]);
            bf16x8 va1 = *reinterpret_cast<const bf16x8*>(&vl[dt * 16 + q4][8 * g + 32]);
            oacc[dt] = __builtin_amdgcn_mfma_f32_16x16x32_bf16(va0, ph0, oacc[dt], 0, 0, 0);
            oacc[dt] = __builtin_amdgcn_mfma_f32_16x16x32_bf16(va1, ph1, oacc[dt], 0, 0, 0);
        }
        __builtin_amdgcn_s_setprio(0);

        // ---- rotate single buffer (block-uniform condition)
        if (c + SEGS < C) {
            barrier_lds();                       // all waves done reading K/V
            writeKV();                           // stage chunk c+SEGS
            int cn = c + 2 * SEGS;
            loadKV((cn < C ? cn : c + SEGS) << 6);   // issue chunk c+2*SEGS
            asm volatile("" ::: "memory");
            barrier_lds();                       // writes visible
        }
    }

    // ---- epilogue.  BARRIER FIRST: ot unions P with different per-wave
    // strides, so a fast wave's ot writes would clobber a slow wave's P
    // mid-PV (this was r12's 0.286 corruption).
    barrier_lds();
    const float invl = 1.0f / l;
    #pragma unroll
    for (int dt = 0; dt < 4; ++dt)
        #pragma unroll
        for (int r = 0; r < 4; ++r)
            ot[w][q4][dt * 16 + 4 * g + r] = (f16_t)(oacc[dt][r] * invl);

    const long pbase = (((long)b * 64 + tile) * SEGS + seg) * 64;
    {
        const int q  = lane >> 2;
        const int dc = (lane & 3) * 16;
        f16x8 o0 = *reinterpret_cast<const f16x8*>(&ot[w][q][dc]);
        f16x8 o1 = *reinterpret_cast<const f16x8*>(&ot[w][q][dc + 8]);
        f16_t* dst = pO + (pbase + 16 * w + q) * 64 + dc;
        *reinterpret_cast<f16x8*>(dst)     = o0;
        *reinterpret_cast<f16x8*>(dst + 8) = o1;
    }
    if (g == 0) {
        pm[pbase + 16 * w + q4] = m;
        pl[pbase + 16 * w + q4] = l;
    }
}

// ---------------------------------------------------------------------------
// merge: combine active segs per 64q tile -> final O (fp32).  exp2 domain.
// ---------------------------------------------------------------------------
__global__ __launch_bounds__(256) void merge_k(
    const f16_t* __restrict__ pO, const float* __restrict__ pm,
    const float* __restrict__ pl, float* __restrict__ O)
{
    const int tile = blockIdx.x, b = blockIdx.y;
    const int C = tile + 1;
    const int S = (C < SEGS) ? C : SEGS;
    const int t = threadIdx.x;
    const int q = t >> 2, dc = (t & 3) * 16;
    const long pb = ((long)b * 64 + tile) * SEGS;

    float mstar = -1e30f;
    for (int s = 0; s < S; ++s) mstar = fmaxf(mstar, pm[(pb + s) * 64 + q]);
    float L = 0.f;
    float o[16];
    #pragma unroll
    for (int i = 0; i < 16; ++i) o[i] = 0.f;
    for (int s = 0; s < S; ++s) {
        const float ws = __builtin_exp2f(pm[(pb + s) * 64 + q] - mstar) * pl[(pb + s) * 64 + q];
        L += ws;
        const f16_t* src = pO + ((pb + s) * 64 + q) * 64 + dc;
        f16x8 a0 = *reinterpret_cast<const f16x8*>(src);
        f16x8 a1 = *reinterpret_cast<const f16x8*>(src + 8);
        #pragma unroll
        for (int i = 0; i < 8; ++i) {
            o[i]     += ws * (float)a0[i];
            o[8 + i] += ws * (float)a1[i];
        }
    }
    const float inv = 1.0f / L;
    float* dst = O + ((long)b * TSEQ + tile * 64 + q) * 64 + dc;
    #pragma unroll
    for (int i = 0; i < 4; ++i) {
        f32x4 v = {o[4*i] * inv, o[4*i+1] * inv, o[4*i+2] * inv, o[4*i+3] * inv};
        *reinterpret_cast<f32x4*>(dst + 4 * i) = v;
    }
}

extern "C" void kernel_launch(void* const* d_in, const int* in_sizes, int n_in,
                              void* d_out, int out_size, void* d_ws, size_t ws_size,
                              hipStream_t stream)
{
    const float* X  = (const float*)d_in[0];
    const float* Wq = (const float*)d_in[1];
    const float* Wk = (const float*)d_in[2];
    const float* Wv = (const float*)d_in[3];
    float* O = (float*)d_out;

    char* ws = (char*)d_ws;
    size_t off = 0;
    bf16_t* wT = (bf16_t*)(ws + off); off += 192 * 1024 * sizeof(bf16_t);
    bf16_t* qh = (bf16_t*)(ws + off); off += 8192L * 64 * sizeof(bf16_t);
    bf16_t* kh = (bf16_t*)(ws + off); off += 8192L * 64 * sizeof(bf16_t);
    bf16_t* vt = (bf16_t*)(ws + off); off += 64L * 8192 * sizeof(bf16_t);
    f16_t*  pO = (f16_t*)(ws + off);  off += 2L * 64 * SEGS * 64 * 64 * sizeof(f16_t);
    float*  pm = (float*)(ws + off);  off += 2L * 64 * SEGS * 64 * sizeof(float);
    float*  pl = (float*)(ws + off);  off += 2L * 64 * SEGS * 64 * sizeof(float);

    wsplit_k <<<48, 256, 0, stream>>>(Wq, Wk, Wv, wT);
    proj_mfma<<<512, 256, 0, stream>>>(X, wT, qh, kh, vt);
    attn_mfma<<<dim3(64 * SEGS, 2), 256, 0, stream>>>(qh, kh, vt, pO, pm, pl);
    merge_k  <<<dim3(64, 2), 256, 0, stream>>>(pO, pm, pl, O);
}